// Round 5
// baseline (635.552 us; speedup 1.0000x reference)
//
#include <hip/hip_runtime.h>

#define BN_EPS 1e-5f

// ---------------------------------------------------------------------------
// Preprocess: build CSR (edges grouped by dst) so aggregation needs no atomics.
// Edge record packed as int2 {src, coef_bits} -> ONE random 8B write/edge.
// After scatter, each node's list is sorted by src so the aggregation's gather
// stream is an ascending sweep -> L2-resident sliding window.
// ---------------------------------------------------------------------------

__global__ void zero_int_kernel(int* __restrict__ p, int n) {
  int i = blockIdx.x * blockDim.x + threadIdx.x;
  if (i < n) p[i] = 0;
}

__global__ void hist_kernel(const int* __restrict__ dst, int* __restrict__ cnt, int E) {
  int e = blockIdx.x * blockDim.x + threadIdx.x;
  if (e < E) atomicAdd(&cnt[dst[e]], 1);
}

// --- 3-phase parallel exclusive scan over N counts ---
__global__ __launch_bounds__(256) void block_sum_kernel(
    const int* __restrict__ cnt, int* __restrict__ bsum, int n) {
  int base = blockIdx.x * 1024 + threadIdx.x * 4;
  int s = 0;
#pragma unroll
  for (int j = 0; j < 4; ++j) {
    int i = base + j;
    if (i < n) s += cnt[i];
  }
#pragma unroll
  for (int o = 32; o > 0; o >>= 1) s += __shfl_down(s, o);
  __shared__ int ws[4];
  int lane = threadIdx.x & 63, w = threadIdx.x >> 6;
  if (lane == 0) ws[w] = s;
  __syncthreads();
  if (threadIdx.x == 0) bsum[blockIdx.x] = ws[0] + ws[1] + ws[2] + ws[3];
}

__global__ void scan_sums_kernel(int* __restrict__ bsum, int nb) {
  int lane = threadIdx.x;
  int v = (lane < nb) ? bsum[lane] : 0;
  int orig = v;
#pragma unroll
  for (int o = 1; o < 64; o <<= 1) {
    int t = __shfl_up(v, o);
    if (lane >= o) v += t;
  }
  if (lane < nb) bsum[lane] = v - orig;  // exclusive prefix
}

__global__ __launch_bounds__(256) void scan_apply_kernel(
    const int* __restrict__ cnt, const int* __restrict__ bsum,
    int* __restrict__ off, int* __restrict__ cursor, float* __restrict__ dinv,
    int n, int E) {
  __shared__ int ts[256];
  const int t = threadIdx.x;
  const int base = blockIdx.x * 1024 + t * 4;
  int c[4];
  int s = 0;
#pragma unroll
  for (int j = 0; j < 4; ++j) {
    int i = base + j;
    c[j] = (i < n) ? cnt[i] : 0;
    s += c[j];
  }
  ts[t] = s;
  __syncthreads();
  for (int o = 1; o < 256; o <<= 1) {
    int v = (t >= o) ? ts[t - o] : 0;
    __syncthreads();
    ts[t] += v;
    __syncthreads();
  }
  int prefix = bsum[blockIdx.x] + ((t == 0) ? 0 : ts[t - 1]);
#pragma unroll
  for (int j = 0; j < 4; ++j) {
    int i = base + j;
    if (i < n) {
      off[i] = prefix;
      cursor[i] = prefix;
      dinv[i] = rsqrtf(1.0f + (float)c[j]);
      prefix += c[j];
    }
  }
  if (blockIdx.x == 0 && t == 0) off[n] = E;
}

__global__ void scatter_kernel(const int* __restrict__ src, const int* __restrict__ dst,
                               const float* __restrict__ dinv, int* __restrict__ cursor,
                               int2* __restrict__ edges, int E) {
  int e = blockIdx.x * blockDim.x + threadIdx.x;
  if (e >= E) return;
  int d = dst[e];
  int s = src[e];
  int pos = atomicAdd(&cursor[d], 1);
  edges[pos] = make_int2(s, __float_as_int(dinv[s] * dinv[d]));
}

// Per-node insertion sort by src (perf-only; correctness does not depend on it).
__global__ void sort_edges_kernel(const int* __restrict__ off,
                                  int2* __restrict__ edges, int n) {
  int i = blockIdx.x * blockDim.x + threadIdx.x;
  if (i >= n) return;
  int s = off[i], e = off[i + 1];
  int d = e - s;
  if (d <= 1 || d > 96) return;  // Poisson(16): P(d>96) ~ 0
  int2 buf[96];
  for (int j = 0; j < d; ++j) buf[j] = edges[s + j];
  for (int j = 1; j < d; ++j) {
    int2 v = buf[j];
    int k = j - 1;
    while (k >= 0 && buf[k].x > v.x) { buf[k + 1] = buf[k]; --k; }
    buf[k + 1] = v;
  }
  for (int j = 0; j < d; ++j) edges[s + j] = buf[j];
}

// ---------------------------------------------------------------------------
// Register-blocked fp32 GEMM: Y[n,FOUT] = X[n,FIN] @ W[FIN,FOUT].
// 128 threads, 64-row tile, 8x8 (or 8x4) per-thread micro-tile.
// EPI: 0 none, 1 bias+relu, 2 bias, 3 bias+BN+relu folded.
// ---------------------------------------------------------------------------

template <int FIN, int FOUT, int EPI>
__global__ __launch_bounds__(128) void gemm_kernel(
    const float* __restrict__ X, const float* __restrict__ W,
    const float* __restrict__ bias, const float* __restrict__ gam,
    const float* __restrict__ bet, const float* __restrict__ mean,
    const float* __restrict__ var, float* __restrict__ Y, int n) {
  constexpr int KC = 32;
  constexpr int MT = 64;
  constexpr int CL = (FOUT == 64) ? 4 : 8;
  constexpr int BROW = 16 * 12;
  __shared__ float at[KC * MT];
  __shared__ float bl[KC * BROW];

  const int t = threadIdx.x;
  const int cg = t & 15;
  const int rg = t >> 4;
  const int m0 = rg * 8;
  const int rowBase = blockIdx.x * MT;

  float acc[8][CL];
#pragma unroll
  for (int i = 0; i < 8; ++i)
#pragma unroll
    for (int j = 0; j < CL; ++j) acc[i][j] = 0.f;

  for (int kc = 0; kc < FIN; kc += KC) {
    __syncthreads();
#pragma unroll
    for (int p = 0; p < 4; ++p) {
      int idx = p * 128 + t;
      int r = idx >> 3;
      int kq = (idx & 7) << 2;
      int row = rowBase + r;
      float4 v = make_float4(0.f, 0.f, 0.f, 0.f);
      if (row < n) v = *(const float4*)(X + (size_t)row * FIN + kc + kq);
      at[(kq + 0) * MT + r] = v.x;
      at[(kq + 1) * MT + r] = v.y;
      at[(kq + 2) * MT + r] = v.z;
      at[(kq + 3) * MT + r] = v.w;
    }
    constexpr int NBV = KC * FOUT / 4 / 128;
#pragma unroll
    for (int p = 0; p < NBV; ++p) {
      int idx = p * 128 + t;
      int kk = idx / (FOUT / 4);
      int c4 = (idx % (FOUT / 4)) << 2;
      float4 v = *(const float4*)(W + (size_t)(kc + kk) * FOUT + c4);
      int g = c4 / CL;
      int j = c4 % CL;
      *(float4*)(&bl[kk * BROW + g * 12 + j]) = v;
    }
    __syncthreads();

#pragma unroll 4
    for (int k = 0; k < KC; ++k) {
      float4 A0 = *(const float4*)(&at[k * MT + m0]);
      float4 A1 = *(const float4*)(&at[k * MT + m0 + 4]);
      float a[8] = {A0.x, A0.y, A0.z, A0.w, A1.x, A1.y, A1.z, A1.w};
      float b[CL];
      float4 B0 = *(const float4*)(&bl[k * BROW + cg * 12]);
      b[0] = B0.x; b[1] = B0.y; b[2] = B0.z; b[3] = B0.w;
      if constexpr (CL == 8) {
        float4 B1 = *(const float4*)(&bl[k * BROW + cg * 12 + 4]);
        b[4] = B1.x; b[5] = B1.y; b[6] = B1.z; b[7] = B1.w;
      }
#pragma unroll
      for (int i = 0; i < 8; ++i)
#pragma unroll
        for (int j = 0; j < CL; ++j) acc[i][j] = fmaf(a[i], b[j], acc[i][j]);
    }
  }

  const int c0 = cg * CL;
  float sc[CL], sh[CL];
#pragma unroll
  for (int j = 0; j < CL; ++j) { sc[j] = 1.f; sh[j] = 0.f; }
  if constexpr (EPI == 1 || EPI == 2) {
#pragma unroll
    for (int j = 0; j < CL; ++j) sh[j] = bias[c0 + j];
  }
  if constexpr (EPI == 3) {
#pragma unroll
    for (int j = 0; j < CL; ++j) {
      float s = gam[c0 + j] * rsqrtf(var[c0 + j] + BN_EPS);
      sc[j] = s;
      sh[j] = (bias[c0 + j] - mean[c0 + j]) * s + bet[c0 + j];
    }
  }

#pragma unroll
  for (int i = 0; i < 8; ++i) {
    int row = rowBase + m0 + i;
    if (row < n) {
      float o[CL];
#pragma unroll
      for (int j = 0; j < CL; ++j) {
        float v = acc[i][j];
        if constexpr (EPI == 0) o[j] = v;
        if constexpr (EPI == 1) o[j] = fmaxf(v + sh[j], 0.f);
        if constexpr (EPI == 2) o[j] = v + sh[j];
        if constexpr (EPI == 3) o[j] = fmaxf(fmaf(v, sc[j], sh[j]), 0.f);
      }
      float* yp = Y + (size_t)row * FOUT + c0;
      *(float4*)yp = make_float4(o[0], o[1], o[2], o[3]);
      if constexpr (CL == 8)
        *(float4*)(yp + 4) = make_float4(o[4], o[5], o[6], o[7]);
    }
  }
}

// ---------------------------------------------------------------------------
// Aggregations: one wave per node, edge loop unrolled x4 (4 gathers in flight).
// Edge lists sorted by src -> gather window slides through L2.
// ---------------------------------------------------------------------------

__global__ __launch_bounds__(256) void agg64_kernel(
    const float* __restrict__ h, const int* __restrict__ off,
    const int2* __restrict__ edges, const float* __restrict__ dinv,
    float* __restrict__ out, int n) {
  int gi = blockIdx.x * 4 + (threadIdx.x >> 6);
  if (gi >= n) return;
  const int lane = threadIdx.x & 63;

  float a = 0.f;
  int e = off[gi];
  const int e1 = off[gi + 1];
  for (; e + 4 <= e1; e += 4) {
    int2 r0 = edges[e], r1 = edges[e + 1], r2 = edges[e + 2], r3 = edges[e + 3];
    float h0 = h[((size_t)r0.x << 6) + lane];
    float h1 = h[((size_t)r1.x << 6) + lane];
    float h2 = h[((size_t)r2.x << 6) + lane];
    float h3 = h[((size_t)r3.x << 6) + lane];
    a = fmaf(__int_as_float(r0.y), h0, a);
    a = fmaf(__int_as_float(r1.y), h1, a);
    a = fmaf(__int_as_float(r2.y), h2, a);
    a = fmaf(__int_as_float(r3.y), h3, a);
  }
  for (; e < e1; ++e) {
    int2 r = edges[e];
    a = fmaf(__int_as_float(r.y), h[((size_t)r.x << 6) + lane], a);
  }
  float di = dinv[gi];
  a = fmaf(di * di, h[((size_t)gi << 6) + lane], a);
  out[((size_t)gi << 6) + lane] = a;
}

__global__ __launch_bounds__(256) void agg128_bn_kernel(
    const float* __restrict__ h, const int* __restrict__ off,
    const int2* __restrict__ edges, const float* __restrict__ dinv,
    const float* __restrict__ bias, const float* __restrict__ gam,
    const float* __restrict__ bet, const float* __restrict__ mean,
    const float* __restrict__ var, float* __restrict__ out, int n) {
  int gi = blockIdx.x * 4 + (threadIdx.x >> 6);
  if (gi >= n) return;
  const int lane = threadIdx.x & 63;
  const int c = lane << 1;

  float ax = 0.f, ay = 0.f;
  int e = off[gi];
  const int e1 = off[gi + 1];
  for (; e + 4 <= e1; e += 4) {
    int2 r0 = edges[e], r1 = edges[e + 1], r2 = edges[e + 2], r3 = edges[e + 3];
    float2 h0 = *(const float2*)(h + ((size_t)r0.x << 7) + c);
    float2 h1 = *(const float2*)(h + ((size_t)r1.x << 7) + c);
    float2 h2 = *(const float2*)(h + ((size_t)r2.x << 7) + c);
    float2 h3 = *(const float2*)(h + ((size_t)r3.x << 7) + c);
    float c0 = __int_as_float(r0.y), c1 = __int_as_float(r1.y);
    float c2 = __int_as_float(r2.y), c3 = __int_as_float(r3.y);
    ax = fmaf(c0, h0.x, ax); ay = fmaf(c0, h0.y, ay);
    ax = fmaf(c1, h1.x, ax); ay = fmaf(c1, h1.y, ay);
    ax = fmaf(c2, h2.x, ax); ay = fmaf(c2, h2.y, ay);
    ax = fmaf(c3, h3.x, ax); ay = fmaf(c3, h3.y, ay);
  }
  for (; e < e1; ++e) {
    int2 r = edges[e];
    float cf = __int_as_float(r.y);
    float2 hv = *(const float2*)(h + ((size_t)r.x << 7) + c);
    ax = fmaf(cf, hv.x, ax);
    ay = fmaf(cf, hv.y, ay);
  }
  float di = dinv[gi];
  float d2 = di * di;
  float2 hs = *(const float2*)(h + ((size_t)gi << 7) + c);
  ax = fmaf(d2, hs.x, ax);
  ay = fmaf(d2, hs.y, ay);

  float2 bv = *(const float2*)(bias + c);
  float2 gv = *(const float2*)(gam + c);
  float2 bev = *(const float2*)(bet + c);
  float2 mv = *(const float2*)(mean + c);
  float2 vv = *(const float2*)(var + c);
  float s0 = gv.x * rsqrtf(vv.x + BN_EPS);
  float s1 = gv.y * rsqrtf(vv.y + BN_EPS);
  float o0 = fmaxf(fmaf(ax + bv.x - mv.x, s0, bev.x), 0.f);
  float o1 = fmaxf(fmaf(ay + bv.y - mv.y, s1, bev.y), 0.f);
  *(float2*)(out + ((size_t)gi << 7) + c) = make_float2(o0, o1);
}

// ---------------------------------------------------------------------------

static inline size_t alignup(size_t x, size_t a) { return (x + a - 1) & ~(a - 1); }

extern "C" void kernel_launch(void* const* d_in, const int* in_sizes, int n_in,
                              void* d_out, int out_size, void* d_ws, size_t ws_size,
                              hipStream_t stream) {
  const float* x   = (const float*)d_in[0];
  const int*   src = (const int*)d_in[1];
  const int*   dst = (const int*)d_in[2];
  const float* W0  = (const float*)d_in[3];
  const float* b0  = (const float*)d_in[4];
  const float* g0  = (const float*)d_in[5];
  const float* be0 = (const float*)d_in[6];
  const float* m0  = (const float*)d_in[7];
  const float* v0  = (const float*)d_in[8];
  const float* W1  = (const float*)d_in[9];
  const float* b1  = (const float*)d_in[10];
  const float* g1  = (const float*)d_in[11];
  const float* be1 = (const float*)d_in[12];
  const float* m1  = (const float*)d_in[13];
  const float* v1  = (const float*)d_in[14];
  const float* W2  = (const float*)d_in[15];
  const float* b2  = (const float*)d_in[16];
  const float* g2  = (const float*)d_in[17];
  const float* be2 = (const float*)d_in[18];
  const float* m2  = (const float*)d_in[19];
  const float* v2  = (const float*)d_in[20];
  const float* Wm1 = (const float*)d_in[21];
  const float* bm1 = (const float*)d_in[22];
  const float* Wm2 = (const float*)d_in[23];
  const float* bm2 = (const float*)d_in[24];

  const int N = in_sizes[0] / 64;
  const int E = in_sizes[1];

  char* p = (char*)d_ws;
  auto take = [&](size_t bytes) {
    char* r = p;
    p += alignup(bytes, 256);
    return r;
  };
  int*   cnt    = (int*)take((size_t)N * 4);
  int*   off    = (int*)take((size_t)(N + 1) * 4);
  int*   cursor = (int*)take((size_t)N * 4);
  float* dinv   = (float*)take((size_t)N * 4);
  int*   bsum   = (int*)take(64 * 4);
  int2*  edges  = (int2*)take((size_t)E * 8);
  float* hA     = (float*)take((size_t)N * 128 * 4);
  float* hB     = (float*)take((size_t)N * 128 * 4);
  float* aggx   = (float*)take((size_t)N * 64 * 4);
  float* yout   = (float*)d_out;

  const int TB = 256;
  const int nb = (N + 1023) / 1024;

  // --- CSR build ---
  zero_int_kernel<<<(N + TB - 1) / TB, TB, 0, stream>>>(cnt, N);
  hist_kernel<<<(E + TB - 1) / TB, TB, 0, stream>>>(dst, cnt, E);
  block_sum_kernel<<<nb, TB, 0, stream>>>(cnt, bsum, N);
  scan_sums_kernel<<<1, 64, 0, stream>>>(bsum, nb);
  scan_apply_kernel<<<nb, TB, 0, stream>>>(cnt, bsum, off, cursor, dinv, N, E);
  scatter_kernel<<<(E + TB - 1) / TB, TB, 0, stream>>>(src, dst, dinv, cursor, edges, E);
  sort_edges_kernel<<<(N + TB - 1) / TB, TB, 0, stream>>>(off, edges, N);

  const int gemmGrid = (N + 63) / 64;
  const int aggGrid = (N + 3) / 4;

  // --- layer 0: aggregate x (64-dim) first, then GEMM + bias/BN/ReLU epilogue
  agg64_kernel<<<aggGrid, TB, 0, stream>>>(x, off, edges, dinv, aggx, N);
  gemm_kernel<64, 128, 3><<<gemmGrid, 128, 0, stream>>>(aggx, W0, b0, g0, be0, m0, v0, hB, N);
  // --- layer 1 ---
  gemm_kernel<128, 128, 0><<<gemmGrid, 128, 0, stream>>>(hB, W1, nullptr, nullptr, nullptr, nullptr, nullptr, hA, N);
  agg128_bn_kernel<<<aggGrid, TB, 0, stream>>>(hA, off, edges, dinv, b1, g1, be1, m1, v1, hB, N);
  // --- layer 2 ---
  gemm_kernel<128, 128, 0><<<gemmGrid, 128, 0, stream>>>(hB, W2, nullptr, nullptr, nullptr, nullptr, nullptr, hA, N);
  agg128_bn_kernel<<<aggGrid, TB, 0, stream>>>(hA, off, edges, dinv, b2, g2, be2, m2, v2, hB, N);
  // --- MLP (unfused, both via fast GEMM) ---
  gemm_kernel<128, 128, 1><<<gemmGrid, 128, 0, stream>>>(hB, Wm1, bm1, nullptr, nullptr, nullptr, nullptr, hA, N);
  gemm_kernel<128, 64, 2><<<gemmGrid, 128, 0, stream>>>(hA, Wm2, bm2, nullptr, nullptr, nullptr, nullptr, yout, N);
}

// Round 6
// 444.911 us; speedup vs baseline: 1.4285x; 1.4285x over previous
//
#include <hip/hip_runtime.h>
#include <hip/hip_fp16.h>

#define BN_EPS 1e-5f

// ---------------------------------------------------------------------------
// Preprocess: build CSR (edges grouped by dst) so aggregation needs no atomics.
// Edge record packed as int2 {src, coef_bits} -> ONE random 8B write/edge.
// (R5 lesson: per-node src-sorting gives NO cross-wave L2 locality and the
//  scratch-spilled sort cost 150us — removed.)
// ---------------------------------------------------------------------------

__global__ void zero_int_kernel(int* __restrict__ p, int n) {
  int i = blockIdx.x * blockDim.x + threadIdx.x;
  if (i < n) p[i] = 0;
}

__global__ void hist_kernel(const int* __restrict__ dst, int* __restrict__ cnt, int E) {
  int e = blockIdx.x * blockDim.x + threadIdx.x;
  if (e < E) atomicAdd(&cnt[dst[e]], 1);
}

// --- 3-phase parallel exclusive scan over N counts ---
__global__ __launch_bounds__(256) void block_sum_kernel(
    const int* __restrict__ cnt, int* __restrict__ bsum, int n) {
  int base = blockIdx.x * 1024 + threadIdx.x * 4;
  int s = 0;
#pragma unroll
  for (int j = 0; j < 4; ++j) {
    int i = base + j;
    if (i < n) s += cnt[i];
  }
#pragma unroll
  for (int o = 32; o > 0; o >>= 1) s += __shfl_down(s, o);
  __shared__ int ws[4];
  int lane = threadIdx.x & 63, w = threadIdx.x >> 6;
  if (lane == 0) ws[w] = s;
  __syncthreads();
  if (threadIdx.x == 0) bsum[blockIdx.x] = ws[0] + ws[1] + ws[2] + ws[3];
}

__global__ void scan_sums_kernel(int* __restrict__ bsum, int nb) {
  int lane = threadIdx.x;
  int v = (lane < nb) ? bsum[lane] : 0;
  int orig = v;
#pragma unroll
  for (int o = 1; o < 64; o <<= 1) {
    int t = __shfl_up(v, o);
    if (lane >= o) v += t;
  }
  if (lane < nb) bsum[lane] = v - orig;  // exclusive prefix
}

__global__ __launch_bounds__(256) void scan_apply_kernel(
    const int* __restrict__ cnt, const int* __restrict__ bsum,
    int* __restrict__ off, int* __restrict__ cursor, float* __restrict__ dinv,
    int n, int E) {
  __shared__ int ts[256];
  const int t = threadIdx.x;
  const int base = blockIdx.x * 1024 + t * 4;
  int c[4];
  int s = 0;
#pragma unroll
  for (int j = 0; j < 4; ++j) {
    int i = base + j;
    c[j] = (i < n) ? cnt[i] : 0;
    s += c[j];
  }
  ts[t] = s;
  __syncthreads();
  for (int o = 1; o < 256; o <<= 1) {
    int v = (t >= o) ? ts[t - o] : 0;
    __syncthreads();
    ts[t] += v;
    __syncthreads();
  }
  int prefix = bsum[blockIdx.x] + ((t == 0) ? 0 : ts[t - 1]);
#pragma unroll
  for (int j = 0; j < 4; ++j) {
    int i = base + j;
    if (i < n) {
      off[i] = prefix;
      cursor[i] = prefix;
      dinv[i] = rsqrtf(1.0f + (float)c[j]);
      prefix += c[j];
    }
  }
  if (blockIdx.x == 0 && t == 0) off[n] = E;
}

__global__ void scatter_kernel(const int* __restrict__ src, const int* __restrict__ dst,
                               const float* __restrict__ dinv, int* __restrict__ cursor,
                               int2* __restrict__ edges, int E) {
  int e = blockIdx.x * blockDim.x + threadIdx.x;
  if (e >= E) return;
  int d = dst[e];
  int s = src[e];
  int pos = atomicAdd(&cursor[d], 1);
  edges[pos] = make_int2(s, __float_as_int(dinv[s] * dinv[d]));
}

// fp32 -> fp16 copy (for the layer-0 gather input)
__global__ void cvt_fp16_kernel(const float* __restrict__ in, __half* __restrict__ out,
                                int n4) {
  int i = blockIdx.x * blockDim.x + threadIdx.x;
  if (i >= n4) return;
  float4 v = *(const float4*)(in + (size_t)i * 4);
  union { __half h[4]; float2 f; } u;
  u.h[0] = __float2half_rn(v.x);
  u.h[1] = __float2half_rn(v.y);
  u.h[2] = __float2half_rn(v.z);
  u.h[3] = __float2half_rn(v.w);
  *(float2*)(out + (size_t)i * 4) = u.f;
}

// ---------------------------------------------------------------------------
// Register-blocked fp32 GEMM: Y[n,FOUT] = X[n,FIN] @ W[FIN,FOUT].
// 128 threads, 64-row tile, 8x8 (or 8x4) per-thread micro-tile.
// EPI: 0 none, 1 bias+relu, 2 bias, 3 bias+BN+relu folded.
// HALFOUT: write Y as fp16 (only consumer is the gather-heavy aggregation).
// ---------------------------------------------------------------------------

template <int FIN, int FOUT, int EPI, bool HALFOUT>
__global__ __launch_bounds__(128) void gemm_kernel(
    const float* __restrict__ X, const float* __restrict__ W,
    const float* __restrict__ bias, const float* __restrict__ gam,
    const float* __restrict__ bet, const float* __restrict__ mean,
    const float* __restrict__ var, void* __restrict__ Yv, int n) {
  constexpr int KC = 32;
  constexpr int MT = 64;
  constexpr int CL = (FOUT == 64) ? 4 : 8;
  constexpr int BROW = 16 * 12;
  __shared__ float at[KC * MT];
  __shared__ float bl[KC * BROW];

  const int t = threadIdx.x;
  const int cg = t & 15;
  const int rg = t >> 4;
  const int m0 = rg * 8;
  const int rowBase = blockIdx.x * MT;

  float acc[8][CL];
#pragma unroll
  for (int i = 0; i < 8; ++i)
#pragma unroll
    for (int j = 0; j < CL; ++j) acc[i][j] = 0.f;

  for (int kc = 0; kc < FIN; kc += KC) {
    __syncthreads();
#pragma unroll
    for (int p = 0; p < 4; ++p) {
      int idx = p * 128 + t;
      int r = idx >> 3;
      int kq = (idx & 7) << 2;
      int row = rowBase + r;
      float4 v = make_float4(0.f, 0.f, 0.f, 0.f);
      if (row < n) v = *(const float4*)(X + (size_t)row * FIN + kc + kq);
      at[(kq + 0) * MT + r] = v.x;
      at[(kq + 1) * MT + r] = v.y;
      at[(kq + 2) * MT + r] = v.z;
      at[(kq + 3) * MT + r] = v.w;
    }
    constexpr int NBV = KC * FOUT / 4 / 128;
#pragma unroll
    for (int p = 0; p < NBV; ++p) {
      int idx = p * 128 + t;
      int kk = idx / (FOUT / 4);
      int c4 = (idx % (FOUT / 4)) << 2;
      float4 v = *(const float4*)(W + (size_t)(kc + kk) * FOUT + c4);
      int g = c4 / CL;
      int j = c4 % CL;
      *(float4*)(&bl[kk * BROW + g * 12 + j]) = v;
    }
    __syncthreads();

#pragma unroll 4
    for (int k = 0; k < KC; ++k) {
      float4 A0 = *(const float4*)(&at[k * MT + m0]);
      float4 A1 = *(const float4*)(&at[k * MT + m0 + 4]);
      float a[8] = {A0.x, A0.y, A0.z, A0.w, A1.x, A1.y, A1.z, A1.w};
      float b[CL];
      float4 B0 = *(const float4*)(&bl[k * BROW + cg * 12]);
      b[0] = B0.x; b[1] = B0.y; b[2] = B0.z; b[3] = B0.w;
      if constexpr (CL == 8) {
        float4 B1 = *(const float4*)(&bl[k * BROW + cg * 12 + 4]);
        b[4] = B1.x; b[5] = B1.y; b[6] = B1.z; b[7] = B1.w;
      }
#pragma unroll
      for (int i = 0; i < 8; ++i)
#pragma unroll
        for (int j = 0; j < CL; ++j) acc[i][j] = fmaf(a[i], b[j], acc[i][j]);
    }
  }

  const int c0 = cg * CL;
  float sc[CL], sh[CL];
#pragma unroll
  for (int j = 0; j < CL; ++j) { sc[j] = 1.f; sh[j] = 0.f; }
  if constexpr (EPI == 1 || EPI == 2) {
#pragma unroll
    for (int j = 0; j < CL; ++j) sh[j] = bias[c0 + j];
  }
  if constexpr (EPI == 3) {
#pragma unroll
    for (int j = 0; j < CL; ++j) {
      float s = gam[c0 + j] * rsqrtf(var[c0 + j] + BN_EPS);
      sc[j] = s;
      sh[j] = (bias[c0 + j] - mean[c0 + j]) * s + bet[c0 + j];
    }
  }

#pragma unroll
  for (int i = 0; i < 8; ++i) {
    int row = rowBase + m0 + i;
    if (row < n) {
      float o[CL];
#pragma unroll
      for (int j = 0; j < CL; ++j) {
        float v = acc[i][j];
        if constexpr (EPI == 0) o[j] = v;
        if constexpr (EPI == 1) o[j] = fmaxf(v + sh[j], 0.f);
        if constexpr (EPI == 2) o[j] = v + sh[j];
        if constexpr (EPI == 3) o[j] = fmaxf(fmaf(v, sc[j], sh[j]), 0.f);
      }
      if constexpr (HALFOUT) {
        __half* Y = (__half*)Yv;
        union { __half h[8]; float4 f; } u;
#pragma unroll
        for (int j = 0; j < CL; ++j) u.h[j] = __float2half_rn(o[j]);
        *(float4*)(Y + (size_t)row * FOUT + c0) = u.f;  // CL==8 -> 16B
      } else {
        float* Y = (float*)Yv;
        float* yp = Y + (size_t)row * FOUT + c0;
        *(float4*)yp = make_float4(o[0], o[1], o[2], o[3]);
        if constexpr (CL == 8)
          *(float4*)(yp + 4) = make_float4(o[4], o[5], o[6], o[7]);
      }
    }
  }
}

// ---------------------------------------------------------------------------
// Aggregations: one wave per node, edge loop unrolled x4 (4 gathers in flight).
// Gather input is fp16 (halves the L2-miss traffic); accumulate fp32.
// ---------------------------------------------------------------------------

__global__ __launch_bounds__(256) void agg64_kernel(
    const __half* __restrict__ h, const int* __restrict__ off,
    const int2* __restrict__ edges, const float* __restrict__ dinv,
    float* __restrict__ out, int n) {
  int gi = blockIdx.x * 4 + (threadIdx.x >> 6);
  if (gi >= n) return;
  const int lane = threadIdx.x & 63;

  float a = 0.f;
  int e = off[gi];
  const int e1 = off[gi + 1];
  for (; e + 4 <= e1; e += 4) {
    int2 r0 = edges[e], r1 = edges[e + 1], r2 = edges[e + 2], r3 = edges[e + 3];
    float h0 = __half2float(h[((size_t)r0.x << 6) + lane]);
    float h1 = __half2float(h[((size_t)r1.x << 6) + lane]);
    float h2 = __half2float(h[((size_t)r2.x << 6) + lane]);
    float h3 = __half2float(h[((size_t)r3.x << 6) + lane]);
    a = fmaf(__int_as_float(r0.y), h0, a);
    a = fmaf(__int_as_float(r1.y), h1, a);
    a = fmaf(__int_as_float(r2.y), h2, a);
    a = fmaf(__int_as_float(r3.y), h3, a);
  }
  for (; e < e1; ++e) {
    int2 r = edges[e];
    a = fmaf(__int_as_float(r.y), __half2float(h[((size_t)r.x << 6) + lane]), a);
  }
  float di = dinv[gi];
  a = fmaf(di * di, __half2float(h[((size_t)gi << 6) + lane]), a);
  out[((size_t)gi << 6) + lane] = a;
}

__global__ __launch_bounds__(256) void agg128_bn_kernel(
    const __half* __restrict__ h, const int* __restrict__ off,
    const int2* __restrict__ edges, const float* __restrict__ dinv,
    const float* __restrict__ bias, const float* __restrict__ gam,
    const float* __restrict__ bet, const float* __restrict__ mean,
    const float* __restrict__ var, float* __restrict__ out, int n) {
  int gi = blockIdx.x * 4 + (threadIdx.x >> 6);
  if (gi >= n) return;
  const int lane = threadIdx.x & 63;
  const int c = lane << 1;
  const __half2* hp = (const __half2*)h;  // row stride 64 half2

  float ax = 0.f, ay = 0.f;
  int e = off[gi];
  const int e1 = off[gi + 1];
  for (; e + 4 <= e1; e += 4) {
    int2 r0 = edges[e], r1 = edges[e + 1], r2 = edges[e + 2], r3 = edges[e + 3];
    float2 h0 = __half22float2(hp[((size_t)r0.x << 6) + lane]);
    float2 h1 = __half22float2(hp[((size_t)r1.x << 6) + lane]);
    float2 h2 = __half22float2(hp[((size_t)r2.x << 6) + lane]);
    float2 h3 = __half22float2(hp[((size_t)r3.x << 6) + lane]);
    float c0 = __int_as_float(r0.y), c1 = __int_as_float(r1.y);
    float c2 = __int_as_float(r2.y), c3 = __int_as_float(r3.y);
    ax = fmaf(c0, h0.x, ax); ay = fmaf(c0, h0.y, ay);
    ax = fmaf(c1, h1.x, ax); ay = fmaf(c1, h1.y, ay);
    ax = fmaf(c2, h2.x, ax); ay = fmaf(c2, h2.y, ay);
    ax = fmaf(c3, h3.x, ax); ay = fmaf(c3, h3.y, ay);
  }
  for (; e < e1; ++e) {
    int2 r = edges[e];
    float cf = __int_as_float(r.y);
    float2 hv = __half22float2(hp[((size_t)r.x << 6) + lane]);
    ax = fmaf(cf, hv.x, ax);
    ay = fmaf(cf, hv.y, ay);
  }
  float di = dinv[gi];
  float d2 = di * di;
  float2 hs = __half22float2(hp[((size_t)gi << 6) + lane]);
  ax = fmaf(d2, hs.x, ax);
  ay = fmaf(d2, hs.y, ay);

  float2 bv = *(const float2*)(bias + c);
  float2 gv = *(const float2*)(gam + c);
  float2 bev = *(const float2*)(bet + c);
  float2 mv = *(const float2*)(mean + c);
  float2 vv = *(const float2*)(var + c);
  float s0 = gv.x * rsqrtf(vv.x + BN_EPS);
  float s1 = gv.y * rsqrtf(vv.y + BN_EPS);
  float o0 = fmaxf(fmaf(ax + bv.x - mv.x, s0, bev.x), 0.f);
  float o1 = fmaxf(fmaf(ay + bv.y - mv.y, s1, bev.y), 0.f);
  *(float2*)(out + ((size_t)gi << 7) + c) = make_float2(o0, o1);
}

// ---------------------------------------------------------------------------

static inline size_t alignup(size_t x, size_t a) { return (x + a - 1) & ~(a - 1); }

extern "C" void kernel_launch(void* const* d_in, const int* in_sizes, int n_in,
                              void* d_out, int out_size, void* d_ws, size_t ws_size,
                              hipStream_t stream) {
  const float* x   = (const float*)d_in[0];
  const int*   src = (const int*)d_in[1];
  const int*   dst = (const int*)d_in[2];
  const float* W0  = (const float*)d_in[3];
  const float* b0  = (const float*)d_in[4];
  const float* g0  = (const float*)d_in[5];
  const float* be0 = (const float*)d_in[6];
  const float* m0  = (const float*)d_in[7];
  const float* v0  = (const float*)d_in[8];
  const float* W1  = (const float*)d_in[9];
  const float* b1  = (const float*)d_in[10];
  const float* g1  = (const float*)d_in[11];
  const float* be1 = (const float*)d_in[12];
  const float* m1  = (const float*)d_in[13];
  const float* v1  = (const float*)d_in[14];
  const float* W2  = (const float*)d_in[15];
  const float* b2  = (const float*)d_in[16];
  const float* g2  = (const float*)d_in[17];
  const float* be2 = (const float*)d_in[18];
  const float* m2  = (const float*)d_in[19];
  const float* v2  = (const float*)d_in[20];
  const float* Wm1 = (const float*)d_in[21];
  const float* bm1 = (const float*)d_in[22];
  const float* Wm2 = (const float*)d_in[23];
  const float* bm2 = (const float*)d_in[24];

  const int N = in_sizes[0] / 64;
  const int E = in_sizes[1];

  char* p = (char*)d_ws;
  auto take = [&](size_t bytes) {
    char* r = p;
    p += alignup(bytes, 256);
    return r;
  };
  int*    cnt    = (int*)take((size_t)N * 4);
  int*    off    = (int*)take((size_t)(N + 1) * 4);
  int*    cursor = (int*)take((size_t)N * 4);
  float*  dinv   = (float*)take((size_t)N * 4);
  int*    bsum   = (int*)take(64 * 4);
  int2*   edges  = (int2*)take((size_t)E * 8);
  float*  hA     = (float*)take((size_t)N * 128 * 4);
  float*  hB     = (float*)take((size_t)N * 128 * 4);
  __half* h16    = (__half*)take((size_t)N * 128 * 2);
  __half* x16    = (__half*)take((size_t)N * 64 * 2);
  float*  aggx   = (float*)take((size_t)N * 64 * 4);
  float*  yout   = (float*)d_out;

  const int TB = 256;
  const int nb = (N + 1023) / 1024;

  // --- CSR build + fp16 copy of x ---
  zero_int_kernel<<<(N + TB - 1) / TB, TB, 0, stream>>>(cnt, N);
  hist_kernel<<<(E + TB - 1) / TB, TB, 0, stream>>>(dst, cnt, E);
  block_sum_kernel<<<nb, TB, 0, stream>>>(cnt, bsum, N);
  scan_sums_kernel<<<1, 64, 0, stream>>>(bsum, nb);
  scan_apply_kernel<<<nb, TB, 0, stream>>>(cnt, bsum, off, cursor, dinv, N, E);
  scatter_kernel<<<(E + TB - 1) / TB, TB, 0, stream>>>(src, dst, dinv, cursor, edges, E);
  {
    int n4 = N * 64 / 4;
    cvt_fp16_kernel<<<(n4 + TB - 1) / TB, TB, 0, stream>>>(x, x16, n4);
  }

  const int gemmGrid = (N + 63) / 64;
  const int aggGrid = (N + 3) / 4;

  // --- layer 0: aggregate x16 (64-dim), then GEMM + bias/BN/ReLU epilogue ---
  agg64_kernel<<<aggGrid, TB, 0, stream>>>(x16, off, edges, dinv, aggx, N);
  gemm_kernel<64, 128, 3, false><<<gemmGrid, 128, 0, stream>>>(
      aggx, W0, b0, g0, be0, m0, v0, hB, N);
  // --- layer 1: GEMM writes fp16; aggregate fp16 -> fp32 hA... ---
  gemm_kernel<128, 128, 0, true><<<gemmGrid, 128, 0, stream>>>(
      hB, W1, nullptr, nullptr, nullptr, nullptr, nullptr, h16, N);
  agg128_bn_kernel<<<aggGrid, TB, 0, stream>>>(h16, off, edges, dinv,
                                               b1, g1, be1, m1, v1, hB, N);
  // --- layer 2 ---
  gemm_kernel<128, 128, 0, true><<<gemmGrid, 128, 0, stream>>>(
      hB, W2, nullptr, nullptr, nullptr, nullptr, nullptr, h16, N);
  agg128_bn_kernel<<<aggGrid, TB, 0, stream>>>(h16, off, edges, dinv,
                                               b2, g2, be2, m2, v2, hB, N);
  // --- MLP (fp32) ---
  gemm_kernel<128, 128, 1, false><<<gemmGrid, 128, 0, stream>>>(
      hB, Wm1, bm1, nullptr, nullptr, nullptr, nullptr, hA, N);
  gemm_kernel<128, 64, 2, false><<<gemmGrid, 128, 0, stream>>>(
      hA, Wm2, bm2, nullptr, nullptr, nullptr, nullptr, yout, N);
}